// Round 5
// baseline (141.289 us; speedup 1.0000x reference)
//
#include <hip/hip_runtime.h>

// Problem constants (fixed by the reference).
constexpr int S1 = 8, S2 = 8, F = 128;
constexpr int BATCH = 2048;
constexpr int ROWS_PER_BRANCH = S1 * (2 + 2 * S2);   // 144
constexpr int ROWS_PER_B = 2 * ROWS_PER_BRANCH;      // 288
constexpr int ROW_LEN = F + 2;                       // 130
constexpr int TOTAL_ROWS = BATCH * ROWS_PER_B;       // 589824
constexpr int CHUNK = 64;                            // rows per wave
constexpr int NCHUNKS = TOTAL_ROWS / CHUNK;          // 9216 (exact)
constexpr int NNODES = 100000;
constexpr int PACK_U32 = NNODES * (F / 2);           // 6.4M u32 = 25.6 MB

typedef float  f32x2 __attribute__((ext_vector_type(2)));
typedef float  f32x4 __attribute__((ext_vector_type(4)));
typedef unsigned int u32;
typedef u32    u32x2 __attribute__((ext_vector_type(2)));

__device__ __forceinline__ u32 bf16_rne(float x) {
    u32 u = __float_as_uint(x);
    return (u + 0x7fffu + ((u >> 16) & 1u)) >> 16;   // round-to-nearest-even
}

// Kernel 1: pack f32 feature table -> bf16 pairs in d_ws.
// tbl[node*64 + L] = pack(bf16(f[2L]), bf16(f[2L+1])). 51.2 MB -> 25.6 MB:
// the gather working set then fits L2-aggregate+L3 and survives the write
// stream, eliminating the HBM re-fetch (R0: FETCH was 3.3x the table).
__global__ __launch_bounds__(256) void gae_pack(
    const float* __restrict__ features, u32* __restrict__ tbl)
{
    const int tid     = blockIdx.x * blockDim.x + threadIdx.x;
    const int nthread = gridDim.x * blockDim.x;
    const f32x4* __restrict__ f4 = (const f32x4*)features;
    for (int j = tid; j < PACK_U32 / 2; j += nthread) {   // 3.2M f32x4 items
        const f32x4 v = f4[j];
        u32x2 p;
        p.x = bf16_rne(v.x) | (bf16_rne(v.y) << 16);
        p.y = bf16_rne(v.z) | (bf16_rne(v.w) << 16);
        *(u32x2*)&tbl[2 * j] = p;
    }
}

// Kernel 2: phase 1 resolves one row per lane (64 parallel index chases);
// phase 2 loops the 64 rows, gathering the packed bf16 row (1 dword/lane),
// expanding to f32, writing 65 aligned f32x2 nontemporal stores per row.
// Row slots: [wf f0][f1 f2]...[f125 f126][f127 wt].
__global__ __launch_bounds__(256) void gae_gather(
    const u32*   __restrict__ tbl,
    const float* __restrict__ in_amnt,
    const float* __restrict__ out_amnt,
    const int*   __restrict__ in_sample,
    const int*   __restrict__ out_sample,
    const int*   __restrict__ node_ids,
    float*       __restrict__ out)
{
    const int lane  = threadIdx.x & 63;
    const int chunk = (int)((blockIdx.x * blockDim.x + threadIdx.x) >> 6);
    if (chunk >= NCHUNKS) return;

    const int rowbase = chunk * CHUNK;
    const int row     = rowbase + lane;

    // ---- Phase 1: per-lane index resolution ----
    const int b  = row / ROWS_PER_B;
    const int r  = row - b * ROWS_PER_B;
    const int d1 = r / ROWS_PER_BRANCH;              // 0='in' branch, 1='out'
    const int rr = r - d1 * ROWS_PER_BRANCH;
    const int s1 = rr / 18;
    const int lr = rr - s1 * 18;

    const int   nid = node_ids[b];
    const int   e1  = nid * S1 + s1;
    const int   n1  = d1 ? out_sample[e1] : in_sample[e1];
    const float w1  = d1 ? out_amnt[e1]   : in_amnt[e1];

    int node; float wf, wt;
    if (lr == 0 || lr == 9) {                        // hub-1 row (twice)
        node = n1; wf = w1; wt = w1 * w1;
    } else if (lr <= 8) {                            // hub-2, in-direction
        const int e2 = n1 * S2 + (lr - 1);
        const float w2 = in_amnt[e2];
        node = in_sample[e2]; wf = w2; wt = w2 * w1;
    } else {                                         // hub-2, out-direction
        const int e2 = n1 * S2 + (lr - 10);
        const float w2 = out_amnt[e2];
        node = out_sample[e2]; wf = w2; wt = w2 * w1;
    }

    // ---- Phase 2: broadcast bf16 gather, expand, f32x2 nt stores ----
    #pragma unroll 8
    for (int t = 0; t < CHUNK; ++t) {
        const int   nd  = __shfl(node, t);
        const float wfb = __shfl(wf,  t);
        const float wtb = __shfl(wt,  t);

        const u32  pv = tbl[(size_t)nd * (F / 2) + lane];     // bf16 f[2L],f[2L+1]
        const float x0 = __uint_as_float(pv << 16);           // f[2L]
        const float x1 = __uint_as_float(pv & 0xffff0000u);   // f[2L+1]
        const float lo = __shfl_up(x1, 1);                    // f[2L-1]

        f32x2* orow2 = (f32x2*)(out + (size_t)(rowbase + t) * ROW_LEN);
        f32x2 slot;
        slot.x = (lane == 0) ? wfb : lo;
        slot.y = x0;
        __builtin_nontemporal_store(slot, &orow2[lane]);
        if (lane == 63) {
            f32x2 tail; tail.x = x1; tail.y = wtb;            // f127, wt
            __builtin_nontemporal_store(tail, &orow2[64]);
        }
    }
}

extern "C" void kernel_launch(void* const* d_in, const int* in_sizes, int n_in,
                              void* d_out, int out_size, void* d_ws, size_t ws_size,
                              hipStream_t stream) {
    const float* features   = (const float*)d_in[0];
    const float* in_amnt    = (const float*)d_in[1];
    const float* out_amnt   = (const float*)d_in[2];
    const int*   in_sample  = (const int*)d_in[3];
    const int*   out_sample = (const int*)d_in[4];
    const int*   node_ids   = (const int*)d_in[5];
    float*       out        = (float*)d_out;
    u32*         tbl        = (u32*)d_ws;            // 25.6 MB of d_ws

    gae_pack<<<2048, 256, 0, stream>>>(features, tbl);
    // Same stream -> pack completes (and L2s flush) before gather starts.
    gae_gather<<<2304, 256, 0, stream>>>(tbl, in_amnt, out_amnt,
                                         in_sample, out_sample, node_ids, out);
}

// Round 6
// 102.555 us; speedup vs baseline: 1.3777x; 1.3777x over previous
//
#include <hip/hip_runtime.h>

// Problem constants (fixed by the reference).
constexpr int S1 = 8, S2 = 8, F = 128;
constexpr int ROWS_PER_BRANCH = S1 * (2 + 2 * S2);   // 144
constexpr int ROWS_PER_B = 2 * ROWS_PER_BRANCH;      // 288
constexpr int ROW_LEN = F + 2;                       // 130
constexpr int TOTAL_ROWS = 2048 * ROWS_PER_B;        // 589824
constexpr int SLOTS = ROW_LEN / 2;                   // 65 f32x2 slots/row
// TOTAL_SLOTS = 589824*65 = 38,338,560 = 9360 blocks * 256 thr * 16 slots
constexpr unsigned TOTAL_THREADS = 9360u * 256u;     // 2,396,160
constexpr int SLOTS_PER_THREAD = 16;

typedef float f32x2 __attribute__((ext_vector_type(2)));
typedef unsigned int u32;

// Kernel 1: resolve every output row's {node, wf, wt} -> meta[] in d_ws.
// One thread per row; the 3-deep index chase runs 590K-wide in parallel.
__global__ __launch_bounds__(256) void gae_meta(
    const float* __restrict__ in_amnt,
    const float* __restrict__ out_amnt,
    const int*   __restrict__ in_sample,
    const int*   __restrict__ out_sample,
    const int*   __restrict__ node_ids,
    int4*        __restrict__ meta)
{
    const int row = blockIdx.x * blockDim.x + threadIdx.x;  // exact grid
    const int b  = row / ROWS_PER_B;
    const int r  = row - b * ROWS_PER_B;
    const int d1 = r / ROWS_PER_BRANCH;              // 0='in' branch, 1='out'
    const int rr = r - d1 * ROWS_PER_BRANCH;
    const int s1 = rr / 18;
    const int lr = rr - s1 * 18;

    const int   nid = node_ids[b];
    const int   e1  = nid * S1 + s1;
    const int   n1  = d1 ? out_sample[e1] : in_sample[e1];
    const float w1  = d1 ? out_amnt[e1]   : in_amnt[e1];

    int node; float wf, wt;
    if (lr == 0 || lr == 9) {                        // hub-1 row (twice)
        node = n1; wf = w1; wt = w1 * w1;
    } else if (lr <= 8) {                            // hub-2, in-direction
        const int e2 = n1 * S2 + (lr - 1);
        const float w2 = in_amnt[e2];
        node = in_sample[e2]; wf = w2; wt = w2 * w1;
    } else {                                         // hub-2, out-direction
        const int e2 = n1 * S2 + (lr - 10);
        const float w2 = out_amnt[e2];
        node = out_sample[e2]; wf = w2; wt = w2 * w1;
    }

    int4 m;
    m.x = node;
    m.y = __float_as_int(wf);
    m.z = __float_as_int(wt);
    m.w = 0;
    meta[row] = m;
}

// Kernel 2: one thread per f32x2 output slot. Slot s -> row=s/65, j=s%65.
// Row slots: [wf f0][f1 f2]...[f125 f126][f127 wt].
// Per-wave stores are 512B contiguous AND 512B aligned (flat slot stream);
// no cross-lane ops; 16 independent slots/thread for deep MLP.
__global__ __launch_bounds__(256) void gae_scatter(
    const float* __restrict__ features,
    const int4*  __restrict__ meta,
    float*       __restrict__ out)
{
    const u32 tid = blockIdx.x * blockDim.x + threadIdx.x;
    f32x2* __restrict__ out2 = (f32x2*)out;

    #pragma unroll 4
    for (int k = 0; k < SLOTS_PER_THREAD; ++k) {
        const u32 s   = tid + (u32)k * TOTAL_THREADS;
        const u32 row = s / 65u;                     // magic-mul div
        const u32 j   = s - row * 65u;

        const int4  m    = meta[row];                // L1-shared across row
        const float wf   = __int_as_float(m.y);
        const float wt   = __int_as_float(m.z);
        const float* __restrict__ frow = features + (size_t)m.x * F;

        const u32 iA = (j == 0u)  ? 0u   : (2u * j - 1u);
        const u32 iB = (j >= 64u) ? 127u : (2u * j);
        const float a  = frow[iA];
        const float bv = frow[iB];

        f32x2 v;
        v.x = (j == 0u)  ? wf : a;
        v.y = (j == 64u) ? wt : bv;
        __builtin_nontemporal_store(v, &out2[s]);
    }
}

extern "C" void kernel_launch(void* const* d_in, const int* in_sizes, int n_in,
                              void* d_out, int out_size, void* d_ws, size_t ws_size,
                              hipStream_t stream) {
    const float* features   = (const float*)d_in[0];
    const float* in_amnt    = (const float*)d_in[1];
    const float* out_amnt   = (const float*)d_in[2];
    const int*   in_sample  = (const int*)d_in[3];
    const int*   out_sample = (const int*)d_in[4];
    const int*   node_ids   = (const int*)d_in[5];
    float*       out        = (float*)d_out;
    int4*        meta       = (int4*)d_ws;           // 9.4 MB of d_ws

    gae_meta<<<TOTAL_ROWS / 256, 256, 0, stream>>>(in_amnt, out_amnt,
                                                   in_sample, out_sample,
                                                   node_ids, meta);
    gae_scatter<<<9360, 256, 0, stream>>>(features, meta, out);
}

// Round 7
// 102.258 us; speedup vs baseline: 1.3817x; 1.0029x over previous
//
#include <hip/hip_runtime.h>

// Problem constants (fixed by the reference).
constexpr int S1 = 8, S2 = 8, F = 128;
constexpr int ROWS_PER_BRANCH = S1 * (2 + 2 * S2);   // 144
constexpr int ROWS_PER_B = 2 * ROWS_PER_BRANCH;      // 288
constexpr int ROW_LEN = F + 2;                       // 130
constexpr int TOTAL_ROWS = 2048 * ROWS_PER_B;        // 589824
// TOTAL f32x2 slots = 589824*65 = 38,338,560 = 9360*256 threads * 16
constexpr unsigned TOTAL_THREADS = 9360u * 256u;     // 2,396,160
constexpr int BATCH_SLOTS = 8;                       // slots per phase-group
constexpr int NGROUPS = 2;                           // 2 x 8 = 16 slots/thread

typedef float f32x2 __attribute__((ext_vector_type(2)));
typedef unsigned int u32;

// Kernel 1: resolve every output row's {node, wf, wt} -> meta[] in d_ws.
__global__ __launch_bounds__(256) void gae_meta(
    const float* __restrict__ in_amnt,
    const float* __restrict__ out_amnt,
    const int*   __restrict__ in_sample,
    const int*   __restrict__ out_sample,
    const int*   __restrict__ node_ids,
    int4*        __restrict__ meta)
{
    const int row = blockIdx.x * blockDim.x + threadIdx.x;  // exact grid
    const int b  = row / ROWS_PER_B;
    const int r  = row - b * ROWS_PER_B;
    const int d1 = r / ROWS_PER_BRANCH;              // 0='in' branch, 1='out'
    const int rr = r - d1 * ROWS_PER_BRANCH;
    const int s1 = rr / 18;
    const int lr = rr - s1 * 18;

    const int   nid = node_ids[b];
    const int   e1  = nid * S1 + s1;
    const int   n1  = d1 ? out_sample[e1] : in_sample[e1];
    const float w1  = d1 ? out_amnt[e1]   : in_amnt[e1];

    int node; float wf, wt;
    if (lr == 0 || lr == 9) {                        // hub-1 row (twice)
        node = n1; wf = w1; wt = w1 * w1;
    } else if (lr <= 8) {                            // hub-2, in-direction
        const int e2 = n1 * S2 + (lr - 1);
        const float w2 = in_amnt[e2];
        node = in_sample[e2]; wf = w2; wt = w2 * w1;
    } else {                                         // hub-2, out-direction
        const int e2 = n1 * S2 + (lr - 10);
        const float w2 = out_amnt[e2];
        node = out_sample[e2]; wf = w2; wt = w2 * w1;
    }

    int4 m;
    m.x = node;
    m.y = __float_as_int(wf);
    m.z = __float_as_int(wt);
    m.w = 0;
    meta[row] = m;
}

// Kernel 2: one thread per f32x2 output slot, flat slot space (every wave's
// stores 512B contiguous+aligned). Phase-split: each 8-slot group issues ALL
// its loads first (24 independent requests in flight), then bursts the 8
// nontemporal stores back-to-back -> fewer HBM read/write turnarounds.
__global__ __launch_bounds__(256) void gae_scatter(
    const float* __restrict__ features,
    const int4*  __restrict__ meta,
    float*       __restrict__ out)
{
    const u32 tid = blockIdx.x * blockDim.x + threadIdx.x;
    f32x2* __restrict__ out2 = (f32x2*)out;

    #pragma unroll
    for (int g = 0; g < NGROUPS; ++g) {
        u32   sv[BATCH_SLOTS];
        float wfv[BATCH_SLOTS], wtv[BATCH_SLOTS];
        float av[BATCH_SLOTS], bv[BATCH_SLOTS];
        u32   jv[BATCH_SLOTS];

        // ---- load phase: all requests independent ----
        #pragma unroll
        for (int k = 0; k < BATCH_SLOTS; ++k) {
            const u32 s   = tid + (u32)(g * BATCH_SLOTS + k) * TOTAL_THREADS;
            const u32 row = s / 65u;                 // magic-mul div
            const u32 j   = s - row * 65u;
            sv[k] = s; jv[k] = j;

            const int4 m = meta[row];                // L1-shared across row
            wfv[k] = __int_as_float(m.y);
            wtv[k] = __int_as_float(m.z);
            const float* __restrict__ frow = features + (size_t)m.x * F;

            const u32 iA = (j == 0u)  ? 0u   : (2u * j - 1u);
            const u32 iB = (j >= 64u) ? 127u : (2u * j);
            av[k] = frow[iA];
            bv[k] = frow[iB];
        }

        // ---- store phase: 8 nt stores burst back-to-back ----
        #pragma unroll
        for (int k = 0; k < BATCH_SLOTS; ++k) {
            f32x2 v;
            v.x = (jv[k] == 0u)  ? wfv[k] : av[k];
            v.y = (jv[k] == 64u) ? wtv[k] : bv[k];
            __builtin_nontemporal_store(v, &out2[sv[k]]);
        }
    }
}

extern "C" void kernel_launch(void* const* d_in, const int* in_sizes, int n_in,
                              void* d_out, int out_size, void* d_ws, size_t ws_size,
                              hipStream_t stream) {
    const float* features   = (const float*)d_in[0];
    const float* in_amnt    = (const float*)d_in[1];
    const float* out_amnt   = (const float*)d_in[2];
    const int*   in_sample  = (const int*)d_in[3];
    const int*   out_sample = (const int*)d_in[4];
    const int*   node_ids   = (const int*)d_in[5];
    float*       out        = (float*)d_out;
    int4*        meta       = (int4*)d_ws;           // 9.4 MB of d_ws

    gae_meta<<<TOTAL_ROWS / 256, 256, 0, stream>>>(in_amnt, out_amnt,
                                                   in_sample, out_sample,
                                                   node_ids, meta);
    gae_scatter<<<9360, 256, 0, stream>>>(features, meta, out);
}